// Round 4
// baseline (727.905 us; speedup 1.0000x reference)
//
#include <hip/hip_runtime.h>
#include <float.h>
#include <math.h>

constexpr int NN  = 30000;   // nodes
constexpr int EE  = 300000;  // edges before self-loops
constexpr int GG  = 1024;    // graphs
constexpr int HID = 256;
constexpr int NH  = 8;       // heads
constexpr int EP  = EE + NN; // edges incl self-loops
constexpr int NP  = 30080;   // padded rows: 235 * 128

typedef short bf16x8 __attribute__((ext_vector_type(8)));
typedef float f32x4 __attribute__((ext_vector_type(4)));

__device__ __forceinline__ void gload_lds16(const void* g, void* l) {
    __builtin_amdgcn_global_load_lds(
        (const __attribute__((address_space(1))) unsigned int*)g,
        (__attribute__((address_space(3))) unsigned int*)l, 16, 0, 0);
}

__device__ __forceinline__ void f2hilo(float x, unsigned short& h, unsigned short& l) {
    unsigned u = __float_as_uint(x);
    h = (unsigned short)(u >> 16);                       // truncated hi
    float hv = __uint_as_float(u & 0xFFFF0000u);
    float r = x - hv;                                    // exact residual
    unsigned v = __float_as_uint(r);
    unsigned rnd = ((v >> 16) & 1u) + 0x7FFFu;           // RNE to bf16
    l = (unsigned short)((v + rnd) >> 16);
}

__device__ __forceinline__ float bf2f(unsigned short u) {
    return __uint_as_float(((unsigned)u) << 16);
}

// monotone float <-> uint map for deterministic atomicMax
__device__ __forceinline__ unsigned fmap(float x) {
    unsigned b = __float_as_uint(x);
    return (b & 0x80000000u) ? ~b : (b | 0x80000000u);
}
__device__ __forceinline__ float funmap(unsigned u) {
    return (u & 0x80000000u) ? __uint_as_float(u ^ 0x80000000u) : __uint_as_float(~u);
}

// fused next-layer attention-logit epilogue: es/ed[node][h] = <x_row, wt[h*2+type]>
// o[4] = this lane's 4 channels (k = lane*4..lane*4+3)
__device__ __forceinline__ void score_epilogue(const float* __restrict__ wt,
                                               const float o[4], int lane, int node,
                                               float* __restrict__ es,
                                               float* __restrict__ ed) {
    float acc[16];
    #pragma unroll
    for (int t = 0; t < 16; ++t) {
        const float4 w = *(const float4*)(wt + t * 256 + lane * 4);
        acc[t] = o[0] * w.x + o[1] * w.y + o[2] * w.z + o[3] * w.w;
    }
    #pragma unroll
    for (int off = 1; off < 64; off <<= 1)
        #pragma unroll
        for (int t = 0; t < 16; ++t) acc[t] += __shfl_xor(acc[t], off, 64);
    if (lane < 8) es[node * NH + lane] = acc[lane * 2];
    else if (lane < 16) ed[node * NH + (lane - 8)] = acc[(lane - 8) * 2 + 1];
}

// ---------------- CSR build ----------------
__global__ void k_hist(const int* __restrict__ edst, int* __restrict__ cnt) {
    int i = blockIdx.x * blockDim.x + threadIdx.x;
    if (i >= EP) return;
    int d = (i < EE) ? edst[i] : (i - EE);
    atomicAdd(&cnt[d], 1);
}

__global__ void k_scan(const int* __restrict__ cnt, int* __restrict__ indptr) {
    __shared__ int wtot[16];
    __shared__ int carry_s;
    int tid = threadIdx.x;
    int lane = tid & 63, wid = tid >> 6;
    if (tid == 0) carry_s = 0;
    __syncthreads();
    for (int base = 0; base < NN; base += 1024) {
        int i = base + tid;
        int v = (i < NN) ? cnt[i] : 0;
        int incl = v;
        #pragma unroll
        for (int off = 1; off < 64; off <<= 1) {
            int t = __shfl_up(incl, off, 64);
            if (lane >= off) incl += t;
        }
        if (lane == 63) wtot[wid] = incl;
        __syncthreads();
        int wpre = 0;
        for (int w = 0; w < wid; ++w) wpre += wtot[w];
        int c = carry_s;
        if (i < NN) indptr[i] = c + wpre + incl - v;  // exclusive
        int tot = 0;
        for (int w = 0; w < 16; ++w) tot += wtot[w];
        __syncthreads();
        if (tid == 0) carry_s = c + tot;
        __syncthreads();
    }
    if (tid == 0) indptr[NN] = carry_s;
}

__global__ void k_fill(const int* __restrict__ esrc, const int* __restrict__ edst,
                       const int* __restrict__ indptr, int* __restrict__ cursor,
                       int* __restrict__ srcs) {
    int i = blockIdx.x * blockDim.x + threadIdx.x;
    if (i >= EP) return;
    int d, s;
    if (i < EE) { d = edst[i]; s = esrc[i]; } else { d = i - EE; s = i - EE; }
    int pos = indptr[d] + atomicAdd(&cursor[d], 1);
    srcs[pos] = s;
}

// sort each segment (deterministic order) + record per-slot dst
__global__ void k_sortseg(int* __restrict__ srcs, const int* __restrict__ indptr,
                          int* __restrict__ dsts) {
    int node = blockIdx.x * blockDim.x + threadIdx.x;
    if (node >= NN) return;
    int b = indptr[node], e = indptr[node + 1];
    for (int i = b + 1; i < e; ++i) {
        int v = srcs[i];
        int j = i - 1;
        while (j >= b && srcs[j] > v) { srcs[j + 1] = srcs[j]; --j; }
        srcs[j + 1] = v;
    }
    for (int i = b; i < e; ++i) dsts[i] = node;
}

__global__ void k_starts(const int* __restrict__ batch, int* __restrict__ starts) {
    int i = blockIdx.x * blockDim.x + threadIdx.x;
    if (i >= NN) return;
    int b = batch[i];
    if (i == 0 || batch[i - 1] != b) starts[b] = i;
    if (i == NN - 1) starts[GG] = NN;
}

// ---------------- weight split fp32 -> bf16 hi/lo ----------------
__global__ void k_wconv(const float* __restrict__ W1, const float* __restrict__ W2,
                        const float* __restrict__ W3, const float* __restrict__ W4,
                        const float* __restrict__ W5,
                        unsigned short* __restrict__ Whi, unsigned short* __restrict__ Wlo) {
    int i = blockIdx.x * blockDim.x + threadIdx.x;  // 0..65535
    int l = blockIdx.y;
    const float* W = (l == 0) ? W1 : (l == 1) ? W2 : (l == 2) ? W3 : (l == 3) ? W4 : W5;
    unsigned short h, lo;
    f2hilo(W[i], h, lo);
    Whi[(size_t)l * 65536 + i] = h;
    Wlo[(size_t)l * 65536 + i] = lo;
}

// ---------------- folded score weights: wt[h*2+type][k] = sum_c a[h,c]*W[h*32+c,k] ----------------
__global__ void k_wtilde(const float* __restrict__ W, const float* __restrict__ as,
                         const float* __restrict__ ad, float* __restrict__ Wt) {
    int t = blockIdx.x;          // 0..15: h*2+type
    int k = threadIdx.x;         // 0..255
    int h = t >> 1, type = t & 1;
    const float* a = type ? ad : as;
    float v = 0.f;
    for (int c = 0; c < 32; ++c)
        v = fmaf(a[h * 32 + c], W[(size_t)(h * 32 + c) * HID + k], v);
    Wt[t * 256 + k] = v;
}

// ---------------- embedding with max_norm=1 -> hi/lo + layer-1 scores ----------------
__global__ void k_embed(const int* __restrict__ ids, const float* __restrict__ emb,
                        const float* __restrict__ wt,
                        unsigned short* __restrict__ Phi, unsigned short* __restrict__ Plo,
                        float* __restrict__ es, float* __restrict__ ed) {
    int w = (blockIdx.x * blockDim.x + threadIdx.x) >> 6;
    if (w >= NN) return;
    int lane = threadIdx.x & 63;
    const float4 v = *(const float4*)(emb + (size_t)ids[w] * HID + lane * 4);
    float ss = v.x * v.x + v.y * v.y + v.z * v.z + v.w * v.w;
    #pragma unroll
    for (int off = 32; off >= 1; off >>= 1) ss += __shfl_xor(ss, off, 64);
    float nrm = sqrtf(ss);
    float sc = fminf(1.0f, 1.0f / (nrm + 1e-12f));
    float o[4] = {v.x * sc, v.y * sc, v.z * sc, v.w * sc};
    ushort4 hv, lv;
    f2hilo(o[0], hv.x, lv.x); f2hilo(o[1], hv.y, lv.y);
    f2hilo(o[2], hv.z, lv.z); f2hilo(o[3], hv.w, lv.w);
    *(ushort4*)(Phi + (size_t)w * HID + lane * 4) = hv;
    *(ushort4*)(Plo + (size_t)w * HID + lane * 4) = lv;
    score_epilogue(wt, o, lane, w, es, ed);
}

// ---------------- split-bf16 MFMA GEMM (pure) ----------------
__global__ __launch_bounds__(256) void k_gemm(const unsigned short* __restrict__ Ahi,
                                              const unsigned short* __restrict__ Alo,
                                              const unsigned short* __restrict__ Bhi,
                                              const unsigned short* __restrict__ Blo,
                                              float* __restrict__ O, int M) {
    __shared__ unsigned short lds[4][128 * 64];  // Ahi, Alo, Bhi, Blo: 16KB each
    const int tid = threadIdx.x;
    const int m0 = blockIdx.x * 128;
    const int n0 = blockIdx.y * 128;
    const int wid = tid >> 6, lane = tid & 63;
    const int wm = wid >> 1, wn = wid & 1;
    const int r16 = lane & 15, kq = lane >> 4;

    f32x4 acc[4][4];
    #pragma unroll
    for (int i = 0; i < 4; ++i)
        #pragma unroll
        for (int j = 0; j < 4; ++j) acc[i][j] = (f32x4){0.f, 0.f, 0.f, 0.f};

    for (int kt = 0; kt < 4; ++kt) {
        const int kk = kt * 64;
        #pragma unroll
        for (int rnd = 0; rnd < 4; ++rnd) {
            int q = rnd * 256 + tid;
            int row = q >> 3, c = q & 7;
            int sc = c ^ (row & 7);
            size_t goffA = (size_t)(m0 + row) * HID + kk + sc * 8;
            size_t goffB = (size_t)(n0 + row) * HID + kk + sc * 8;
            gload_lds16(Ahi + goffA, &lds[0][q * 8]);
            gload_lds16(Alo + goffA, &lds[1][q * 8]);
            gload_lds16(Bhi + goffB, &lds[2][q * 8]);
            gload_lds16(Blo + goffB, &lds[3][q * 8]);
        }
        __syncthreads();
        #pragma unroll
        for (int ks = 0; ks < 2; ++ks) {
            bf16x8 ah[4], al[4], bh[4], bl[4];
            #pragma unroll
            for (int f = 0; f < 4; ++f) {
                int rowa = wm * 64 + f * 16 + r16;
                int ca = (ks * 4 + kq) ^ (rowa & 7);
                int offa = rowa * 64 + ca * 8;
                ah[f] = *(const bf16x8*)&lds[0][offa];
                al[f] = *(const bf16x8*)&lds[1][offa];
                int rowb = wn * 64 + f * 16 + r16;
                int cb = (ks * 4 + kq) ^ (rowb & 7);
                int offb = rowb * 64 + cb * 8;
                bh[f] = *(const bf16x8*)&lds[2][offb];
                bl[f] = *(const bf16x8*)&lds[3][offb];
            }
            #pragma unroll
            for (int mi = 0; mi < 4; ++mi)
                #pragma unroll
                for (int ni = 0; ni < 4; ++ni) {
                    acc[mi][ni] = __builtin_amdgcn_mfma_f32_16x16x32_bf16(ah[mi], bh[ni], acc[mi][ni], 0, 0, 0);
                    acc[mi][ni] = __builtin_amdgcn_mfma_f32_16x16x32_bf16(ah[mi], bl[ni], acc[mi][ni], 0, 0, 0);
                    acc[mi][ni] = __builtin_amdgcn_mfma_f32_16x16x32_bf16(al[mi], bh[ni], acc[mi][ni], 0, 0, 0);
                }
        }
        __syncthreads();
    }
    // C/D layout: col = lane&15, row = (lane>>4)*4 + reg  [m89-verified]
    #pragma unroll
    for (int mi = 0; mi < 4; ++mi) {
        #pragma unroll
        for (int q = 0; q < 4; ++q) {
            int row = m0 + wm * 64 + mi * 16 + kq * 4 + q;
            if (row < M) {
                #pragma unroll
                for (int ni = 0; ni < 4; ++ni)
                    O[(size_t)row * HID + n0 + wn * 64 + ni * 16 + r16] = acc[mi][ni][q];
            }
        }
    }
}

// ---------------- edge logits in CSR-slot order + deterministic segment max ----------------
__global__ void k_edge(const int* __restrict__ srcs, const int* __restrict__ dsts,
                       const float* __restrict__ es, const float* __restrict__ ed,
                       float* __restrict__ elog, unsigned* __restrict__ mU) {
    int t = blockIdx.x * blockDim.x + threadIdx.x;
    if (t >= EP * NH) return;
    int j = t >> 3, h = t & 7;
    int s = srcs[j], d = dsts[j];
    float e = es[s * NH + h] + ed[d * NH + h];
    e = (e > 0.f) ? e : 0.2f * e;
    elog[t] = e;
    atomicMax(&mU[d * NH + h], fmap(e));
}

// ---------------- single-pass weighted aggregate + bias + relu -> hi/lo + next scores ----------------
__global__ __launch_bounds__(256) void k_aggregate(const float* __restrict__ H,
                                                   const float* __restrict__ elog,
                                                   const unsigned* __restrict__ mU,
                                                   const int* __restrict__ indptr,
                                                   const int* __restrict__ srcs,
                                                   const float* __restrict__ bias,
                                                   const float* __restrict__ wt,  // next-layer folded scores or null
                                                   unsigned short* __restrict__ Phi,
                                                   unsigned short* __restrict__ Plo,
                                                   float* __restrict__ es,
                                                   float* __restrict__ ed) {
    int node = (blockIdx.x * blockDim.x + threadIdx.x) >> 6;
    if (node >= NN) return;
    int lane = threadIdx.x & 63;
    int head = lane >> 3;
    int b0 = indptr[node], e0 = indptr[node + 1];
    float m = funmap(mU[node * NH + head]);
    float4 a[8];
    float s[8];
    #pragma unroll
    for (int u = 0; u < 8; ++u) { a[u] = (float4){0.f, 0.f, 0.f, 0.f}; s[u] = 0.f; }
    int j = b0;
    for (; j + 7 < e0; j += 8) {
        #pragma unroll
        for (int u = 0; u < 8; ++u) {
            int x = srcs[j + u];
            float ev = elog[(size_t)(j + u) * NH + head];
            float4 hv = *(const float4*)(H + (size_t)x * HID + lane * 4);
            float w = expf(ev - m);
            s[u] += w;
            a[u].x = fmaf(w, hv.x, a[u].x); a[u].y = fmaf(w, hv.y, a[u].y);
            a[u].z = fmaf(w, hv.z, a[u].z); a[u].w = fmaf(w, hv.w, a[u].w);
        }
    }
    for (; j < e0; ++j) {
        int x = srcs[j];
        float ev = elog[(size_t)j * NH + head];
        float4 hv = *(const float4*)(H + (size_t)x * HID + lane * 4);
        float w = expf(ev - m);
        s[0] += w;
        a[0].x = fmaf(w, hv.x, a[0].x); a[0].y = fmaf(w, hv.y, a[0].y);
        a[0].z = fmaf(w, hv.z, a[0].z); a[0].w = fmaf(w, hv.w, a[0].w);
    }
    float sum = ((s[0] + s[1]) + (s[2] + s[3])) + ((s[4] + s[5]) + (s[6] + s[7]));
    float ax = ((a[0].x + a[1].x) + (a[2].x + a[3].x)) + ((a[4].x + a[5].x) + (a[6].x + a[7].x));
    float ay = ((a[0].y + a[1].y) + (a[2].y + a[3].y)) + ((a[4].y + a[5].y) + (a[6].y + a[7].y));
    float az = ((a[0].z + a[1].z) + (a[2].z + a[3].z)) + ((a[4].z + a[5].z) + (a[6].z + a[7].z));
    float aw = ((a[0].w + a[1].w) + (a[2].w + a[3].w)) + ((a[4].w + a[5].w) + (a[6].w + a[7].w));
    float inv = 1.f / (sum + 1e-16f);
    float4 bv = *(const float4*)(bias + lane * 4);
    float o[4];
    o[0] = fmaxf(fmaf(ax, inv, bv.x), 0.f);
    o[1] = fmaxf(fmaf(ay, inv, bv.y), 0.f);
    o[2] = fmaxf(fmaf(az, inv, bv.z), 0.f);
    o[3] = fmaxf(fmaf(aw, inv, bv.w), 0.f);
    ushort4 hv, lv;
    f2hilo(o[0], hv.x, lv.x); f2hilo(o[1], hv.y, lv.y);
    f2hilo(o[2], hv.z, lv.z); f2hilo(o[3], hv.w, lv.w);
    *(ushort4*)(Phi + (size_t)node * HID + lane * 4) = hv;
    *(ushort4*)(Plo + (size_t)node * HID + lane * 4) = lv;
    if (wt) score_epilogue(wt, o, lane, node, es, ed);
}

// ---------------- per-graph max pool + linear head ----------------
__global__ void k_pool(const unsigned short* __restrict__ Phi,
                       const unsigned short* __restrict__ Plo,
                       const int* __restrict__ starts,
                       const float* __restrict__ fw, const float* __restrict__ fb,
                       float* __restrict__ out) {
    int g = (blockIdx.x * blockDim.x + threadIdx.x) >> 6;
    if (g >= GG) return;
    int lane = threadIdx.x & 63;
    int s = starts[g], e = starts[g + 1];
    float mx0 = -FLT_MAX, mx1 = -FLT_MAX, mx2 = -FLT_MAX, mx3 = -FLT_MAX;
    for (int n = s; n < e; ++n) {
        ushort4 hv = *(const ushort4*)(Phi + (size_t)n * HID + lane * 4);
        ushort4 lv = *(const ushort4*)(Plo + (size_t)n * HID + lane * 4);
        mx0 = fmaxf(mx0, bf2f(hv.x) + bf2f(lv.x));
        mx1 = fmaxf(mx1, bf2f(hv.y) + bf2f(lv.y));
        mx2 = fmaxf(mx2, bf2f(hv.z) + bf2f(lv.z));
        mx3 = fmaxf(mx3, bf2f(hv.w) + bf2f(lv.w));
    }
    float4 w = *(const float4*)(fw + lane * 4);
    float t = mx0 * w.x + mx1 * w.y + mx2 * w.z + mx3 * w.w;
    #pragma unroll
    for (int off = 32; off >= 1; off >>= 1) t += __shfl_xor(t, off, 64);
    if (lane == 0) out[g] = t + fb[0];
}

// ---------------- launcher ----------------
extern "C" void kernel_launch(void* const* d_in, const int* in_sizes, int n_in,
                              void* d_out, int out_size, void* d_ws, size_t ws_size,
                              hipStream_t stream) {
    const int* x_ids = (const int*)d_in[0];
    const int* eidx  = (const int*)d_in[1];
    const int* batch = (const int*)d_in[2];
    const float* emb = (const float*)d_in[3];
    const float* fw  = (const float*)d_in[4];
    const float* fb  = (const float*)d_in[5];
    const float* Wl[5], *asl[5], *adl[5], *bl[5];
    for (int l = 0; l < 5; ++l) {
        Wl[l]  = (const float*)d_in[6 + 4 * l];
        asl[l] = (const float*)d_in[7 + 4 * l];
        adl[l] = (const float*)d_in[8 + 4 * l];
        bl[l]  = (const float*)d_in[9 + 4 * l];
    }

    char* ws = (char*)d_ws;
    size_t off = 0;
    auto alloc = [&](size_t bytes) {
        void* p = ws + off;
        off = (off + bytes + 255) & ~(size_t)255;
        return p;
    };
    unsigned short* Phi = (unsigned short*)alloc((size_t)NP * HID * 2);
    unsigned short* Plo = (unsigned short*)alloc((size_t)NP * HID * 2);
    float* Q    = (float*)alloc((size_t)NN * HID * 4);
    unsigned short* Whi = (unsigned short*)alloc((size_t)5 * HID * HID * 2);
    unsigned short* Wlo = (unsigned short*)alloc((size_t)5 * HID * HID * 2);
    float* Wt   = (float*)alloc((size_t)5 * 16 * HID * 4);
    float* es   = (float*)alloc((size_t)NN * NH * 4);
    float* ed   = (float*)alloc((size_t)NN * NH * 4);
    float* elog = (float*)alloc((size_t)EP * NH * 4);
    unsigned* mU = (unsigned*)alloc((size_t)5 * NN * NH * 4);
    int* cnt    = (int*)alloc((size_t)NN * 4);
    int* cursor = (int*)alloc((size_t)NN * 4);
    int* indptr = (int*)alloc((size_t)(NN + 1) * 4);
    int* srcs   = (int*)alloc((size_t)EP * 4);
    int* dsts   = (int*)alloc((size_t)EP * 4);
    int* starts = (int*)alloc((size_t)(GG + 1) * 4);
    (void)ws_size; (void)in_sizes; (void)n_in; (void)out_size;

    hipMemsetAsync(cnt, 0, (size_t)NN * 4, stream);
    hipMemsetAsync(cursor, 0, (size_t)NN * 4, stream);
    hipMemsetAsync(mU, 0, (size_t)5 * NN * NH * 4, stream);  // 0 < fmap(any float)

    k_hist<<<(EP + 255) / 256, 256, 0, stream>>>(eidx + EE, cnt);
    k_scan<<<1, 1024, 0, stream>>>(cnt, indptr);
    k_fill<<<(EP + 255) / 256, 256, 0, stream>>>(eidx, eidx + EE, indptr, cursor, srcs);
    k_sortseg<<<(NN + 255) / 256, 256, 0, stream>>>(srcs, indptr, dsts);
    k_starts<<<(NN + 255) / 256, 256, 0, stream>>>(batch, starts);
    k_wconv<<<dim3(HID * HID / 256, 5), 256, 0, stream>>>(Wl[0], Wl[1], Wl[2], Wl[3], Wl[4], Whi, Wlo);
    for (int l = 0; l < 5; ++l)
        k_wtilde<<<16, 256, 0, stream>>>(Wl[l], asl[l], adl[l], Wt + (size_t)l * 16 * HID);
    k_embed<<<NN / 4, 256, 0, stream>>>(x_ids, emb, Wt, Phi, Plo, es, ed);

    for (int l = 0; l < 5; ++l) {
        unsigned* mUl = mU + (size_t)l * NN * NH;
        k_edge<<<(EP * NH + 255) / 256, 256, 0, stream>>>(srcs, dsts, es, ed, elog, mUl);
        dim3 gg(NP / 128, HID / 128);
        k_gemm<<<gg, 256, 0, stream>>>(Phi, Plo, Whi + (size_t)l * HID * HID,
                                       Wlo + (size_t)l * HID * HID, Q, NN);
        const float* wtn = (l < 4) ? (Wt + (size_t)(l + 1) * 16 * HID) : nullptr;
        k_aggregate<<<NN / 4, 256, 0, stream>>>(Q, elog, mUl, indptr, srcs, bl[l], wtn, Phi, Plo, es, ed);
    }
    k_pool<<<GG / 4, 256, 0, stream>>>(Phi, Plo, starts, fw, fb, (float*)d_out);
}

// Round 5
// 527.797 us; speedup vs baseline: 1.3791x; 1.3791x over previous
//
#include <hip/hip_runtime.h>
#include <float.h>
#include <math.h>

constexpr int NN  = 30000;   // nodes
constexpr int EE  = 300000;  // edges before self-loops
constexpr int GG  = 1024;    // graphs
constexpr int HID = 256;
constexpr int NH  = 8;       // heads
constexpr int EP  = EE + NN; // edges incl self-loops
constexpr int NP  = 30080;   // padded rows: 235 * 128

typedef short bf16x8 __attribute__((ext_vector_type(8)));
typedef float f32x4 __attribute__((ext_vector_type(4)));

__device__ __forceinline__ void gload_lds16(const void* g, void* l) {
    __builtin_amdgcn_global_load_lds(
        (const __attribute__((address_space(1))) unsigned int*)g,
        (__attribute__((address_space(3))) unsigned int*)l, 16, 0, 0);
}

__device__ __forceinline__ void f2hilo(float x, unsigned short& h, unsigned short& l) {
    unsigned u = __float_as_uint(x);
    h = (unsigned short)(u >> 16);                       // truncated hi
    float hv = __uint_as_float(u & 0xFFFF0000u);
    float r = x - hv;                                    // exact residual
    unsigned v = __float_as_uint(r);
    unsigned rnd = ((v >> 16) & 1u) + 0x7FFFu;           // RNE to bf16
    l = (unsigned short)((v + rnd) >> 16);
}

__device__ __forceinline__ float bf2f(unsigned short u) {
    return __uint_as_float(((unsigned)u) << 16);
}

// ---------------- CSR build ----------------
__global__ void k_hist(const int* __restrict__ edst, int* __restrict__ cnt) {
    int i = blockIdx.x * blockDim.x + threadIdx.x;
    if (i >= EP) return;
    int d = (i < EE) ? edst[i] : (i - EE);
    atomicAdd(&cnt[d], 1);
}

__global__ void k_scan(const int* __restrict__ cnt, int* __restrict__ indptr) {
    __shared__ int wtot[16];
    __shared__ int carry_s;
    int tid = threadIdx.x;
    int lane = tid & 63, wid = tid >> 6;
    if (tid == 0) carry_s = 0;
    __syncthreads();
    for (int base = 0; base < NN; base += 1024) {
        int i = base + tid;
        int v = (i < NN) ? cnt[i] : 0;
        int incl = v;
        #pragma unroll
        for (int off = 1; off < 64; off <<= 1) {
            int t = __shfl_up(incl, off, 64);
            if (lane >= off) incl += t;
        }
        if (lane == 63) wtot[wid] = incl;
        __syncthreads();
        int wpre = 0;
        for (int w = 0; w < wid; ++w) wpre += wtot[w];
        int c = carry_s;
        if (i < NN) indptr[i] = c + wpre + incl - v;  // exclusive
        int tot = 0;
        for (int w = 0; w < 16; ++w) tot += wtot[w];
        __syncthreads();
        if (tid == 0) carry_s = c + tot;
        __syncthreads();
    }
    if (tid == 0) indptr[NN] = carry_s;
}

__global__ void k_fill(const int* __restrict__ esrc, const int* __restrict__ edst,
                       const int* __restrict__ indptr, int* __restrict__ cursor,
                       int* __restrict__ srcs) {
    int i = blockIdx.x * blockDim.x + threadIdx.x;
    if (i >= EP) return;
    int d, s;
    if (i < EE) { d = edst[i]; s = esrc[i]; } else { d = i - EE; s = i - EE; }
    int pos = indptr[d] + atomicAdd(&cursor[d], 1);
    srcs[pos] = s;
}

// sort each segment -> deterministic slot order independent of atomic timing
__global__ void k_sortseg(int* __restrict__ srcs, const int* __restrict__ indptr) {
    int node = blockIdx.x * blockDim.x + threadIdx.x;
    if (node >= NN) return;
    int b = indptr[node], e = indptr[node + 1];
    for (int i = b + 1; i < e; ++i) {
        int v = srcs[i];
        int j = i - 1;
        while (j >= b && srcs[j] > v) { srcs[j + 1] = srcs[j]; --j; }
        srcs[j + 1] = v;
    }
}

__global__ void k_starts(const int* __restrict__ batch, int* __restrict__ starts) {
    int i = blockIdx.x * blockDim.x + threadIdx.x;
    if (i >= NN) return;
    int b = batch[i];
    if (i == 0 || batch[i - 1] != b) starts[b] = i;
    if (i == NN - 1) starts[GG] = NN;
}

// ---------------- weight split fp32 -> bf16 hi/lo ----------------
__global__ void k_wconv(const float* __restrict__ W1, const float* __restrict__ W2,
                        const float* __restrict__ W3, const float* __restrict__ W4,
                        const float* __restrict__ W5,
                        unsigned short* __restrict__ Whi, unsigned short* __restrict__ Wlo) {
    int i = blockIdx.x * blockDim.x + threadIdx.x;  // 0..65535
    int l = blockIdx.y;
    const float* W = (l == 0) ? W1 : (l == 1) ? W2 : (l == 2) ? W3 : (l == 3) ? W4 : W5;
    unsigned short h, lo;
    f2hilo(W[i], h, lo);
    Whi[(size_t)l * 65536 + i] = h;
    Wlo[(size_t)l * 65536 + i] = lo;
}

// folded score weights: wt[t][k] = sum_c a[h,c]*W[h*32+c,k], t = h*2+type; bf16 hi/lo
__global__ void k_wtilde(const float* __restrict__ W, const float* __restrict__ as,
                         const float* __restrict__ ad,
                         unsigned short* __restrict__ Wthi, unsigned short* __restrict__ Wtlo) {
    int t = blockIdx.x;          // 0..15
    int k = threadIdx.x;         // 0..255
    int h = t >> 1, type = t & 1;
    const float* a = type ? ad : as;
    float v = 0.f;
    for (int c = 0; c < 32; ++c)
        v = fmaf(a[h * 32 + c], W[(size_t)(h * 32 + c) * HID + k], v);
    unsigned short hi, lo;
    f2hilo(v, hi, lo);
    Wthi[t * 256 + k] = hi;
    Wtlo[t * 256 + k] = lo;
}

// ---------------- embedding with max_norm=1 -> hi/lo ----------------
__global__ void k_embed(const int* __restrict__ ids, const float* __restrict__ emb,
                        unsigned short* __restrict__ Phi, unsigned short* __restrict__ Plo) {
    int w = (blockIdx.x * blockDim.x + threadIdx.x) >> 6;
    if (w >= NN) return;
    int lane = threadIdx.x & 63;
    const float4 v = *(const float4*)(emb + (size_t)ids[w] * HID + lane * 4);
    float ss = v.x * v.x + v.y * v.y + v.z * v.z + v.w * v.w;
    #pragma unroll
    for (int off = 32; off >= 1; off >>= 1) ss += __shfl_xor(ss, off, 64);
    float nrm = sqrtf(ss);
    float sc = fminf(1.0f, 1.0f / (nrm + 1e-12f));
    float o[4] = {v.x * sc, v.y * sc, v.z * sc, v.w * sc};
    ushort4 hv, lv;
    f2hilo(o[0], hv.x, lv.x); f2hilo(o[1], hv.y, lv.y);
    f2hilo(o[2], hv.z, lv.z); f2hilo(o[3], hv.w, lv.w);
    *(ushort4*)(Phi + (size_t)w * HID + lane * 4) = hv;
    *(ushort4*)(Plo + (size_t)w * HID + lane * 4) = lv;
}

// ---------------- split-bf16 MFMA GEMM + fused folded-score columns ----------------
// O[M,256] = (hi+lo)X @ (hi+lo)W^T
// blocks with blockIdx.y==1 additionally compute es/ed[m,t] = X[m]·Wt[t] (16 cols),
// ks halves split across the two wave-columns, combined via LDS.
__global__ __launch_bounds__(256) void k_gemm(const unsigned short* __restrict__ Ahi,
                                              const unsigned short* __restrict__ Alo,
                                              const unsigned short* __restrict__ Bhi,
                                              const unsigned short* __restrict__ Blo,
                                              const unsigned short* __restrict__ Wthi,
                                              const unsigned short* __restrict__ Wtlo,
                                              float* __restrict__ O,
                                              float* __restrict__ es,
                                              float* __restrict__ ed, int M) {
    __shared__ unsigned short lds[4][128 * 64];  // Ahi, Alo, Bhi, Blo: 16KB each
    const int tid = threadIdx.x;
    const int m0 = blockIdx.x * 128;
    const int n0 = blockIdx.y * 128;
    const int wid = tid >> 6, lane = tid & 63;
    const int wm = wid >> 1, wn = wid & 1;
    const int r16 = lane & 15, kq = lane >> 4;
    const bool doScore = (blockIdx.y == 1);

    f32x4 acc[4][4];
    f32x4 acc_s[4];
    #pragma unroll
    for (int i = 0; i < 4; ++i) {
        acc_s[i] = (f32x4){0.f, 0.f, 0.f, 0.f};
        #pragma unroll
        for (int j = 0; j < 4; ++j) acc[i][j] = (f32x4){0.f, 0.f, 0.f, 0.f};
    }

    for (int kt = 0; kt < 4; ++kt) {
        const int kk = kt * 64;
        #pragma unroll
        for (int rnd = 0; rnd < 4; ++rnd) {
            int q = rnd * 256 + tid;
            int row = q >> 3, c = q & 7;
            int sc = c ^ (row & 7);
            size_t goffA = (size_t)(m0 + row) * HID + kk + sc * 8;
            size_t goffB = (size_t)(n0 + row) * HID + kk + sc * 8;
            gload_lds16(Ahi + goffA, &lds[0][q * 8]);
            gload_lds16(Alo + goffA, &lds[1][q * 8]);
            gload_lds16(Bhi + goffB, &lds[2][q * 8]);
            gload_lds16(Blo + goffB, &lds[3][q * 8]);
        }
        __syncthreads();
        #pragma unroll
        for (int ks = 0; ks < 2; ++ks) {
            bf16x8 ah[4], al[4], bh[4], bl[4];
            #pragma unroll
            for (int f = 0; f < 4; ++f) {
                int rowa = wm * 64 + f * 16 + r16;
                int ca = (ks * 4 + kq) ^ (rowa & 7);
                int offa = rowa * 64 + ca * 8;
                ah[f] = *(const bf16x8*)&lds[0][offa];
                al[f] = *(const bf16x8*)&lds[1][offa];
                int rowb = wn * 64 + f * 16 + r16;
                int cb = (ks * 4 + kq) ^ (rowb & 7);
                int offb = rowb * 64 + cb * 8;
                bh[f] = *(const bf16x8*)&lds[2][offb];
                bl[f] = *(const bf16x8*)&lds[3][offb];
            }
            #pragma unroll
            for (int mi = 0; mi < 4; ++mi)
                #pragma unroll
                for (int ni = 0; ni < 4; ++ni) {
                    acc[mi][ni] = __builtin_amdgcn_mfma_f32_16x16x32_bf16(ah[mi], bh[ni], acc[mi][ni], 0, 0, 0);
                    acc[mi][ni] = __builtin_amdgcn_mfma_f32_16x16x32_bf16(ah[mi], bl[ni], acc[mi][ni], 0, 0, 0);
                    acc[mi][ni] = __builtin_amdgcn_mfma_f32_16x16x32_bf16(al[mi], bh[ni], acc[mi][ni], 0, 0, 0);
                }
            if (doScore && wn == ks) {
                const size_t wtoff = (size_t)r16 * HID + kk + ks * 32 + kq * 8;
                bf16x8 wth = *(const bf16x8*)(Wthi + wtoff);
                bf16x8 wtl = *(const bf16x8*)(Wtlo + wtoff);
                #pragma unroll
                for (int mi = 0; mi < 4; ++mi) {
                    acc_s[mi] = __builtin_amdgcn_mfma_f32_16x16x32_bf16(ah[mi], wth, acc_s[mi], 0, 0, 0);
                    acc_s[mi] = __builtin_amdgcn_mfma_f32_16x16x32_bf16(ah[mi], wtl, acc_s[mi], 0, 0, 0);
                    acc_s[mi] = __builtin_amdgcn_mfma_f32_16x16x32_bf16(al[mi], wth, acc_s[mi], 0, 0, 0);
                }
            }
        }
        __syncthreads();
    }
    // C/D layout: col = lane&15, row = (lane>>4)*4 + reg  [m89-verified]
    #pragma unroll
    for (int mi = 0; mi < 4; ++mi) {
        #pragma unroll
        for (int q = 0; q < 4; ++q) {
            int row = m0 + wm * 64 + mi * 16 + kq * 4 + q;
            if (row < M) {
                #pragma unroll
                for (int ni = 0; ni < 4; ++ni)
                    O[(size_t)row * HID + n0 + wn * 64 + ni * 16 + r16] = acc[mi][ni][q];
            }
        }
    }
    if (doScore) {
        // combine ks-halves: wn==1 writes partials, wn==0 adds + stores
        float* sl = (float*)&lds[0][0];  // 8KB scratch, main loop done
        if (wn == 1) {
            #pragma unroll
            for (int mi = 0; mi < 4; ++mi)
                *(f32x4*)&sl[((wm * 4 + mi) * 64 + lane) * 4] = acc_s[mi];
        }
        __syncthreads();
        if (wn == 0) {
            #pragma unroll
            for (int mi = 0; mi < 4; ++mi) {
                f32x4 o = *(const f32x4*)&sl[((wm * 4 + mi) * 64 + lane) * 4];
                o += acc_s[mi];
                int h = r16 >> 1;
                #pragma unroll
                for (int q = 0; q < 4; ++q) {
                    int row = m0 + wm * 64 + mi * 16 + kq * 4 + q;
                    if (row < M) {
                        if ((r16 & 1) == 0) es[row * NH + h] = o[q];
                        else               ed[row * NH + h] = o[q];
                    }
                }
            }
        }
    }
}

// ---------------- single-pass softmax-aggregate (shift-invariant, no max) ----------------
__global__ __launch_bounds__(256) void k_aggregate(const float* __restrict__ H,
                                                   const float* __restrict__ es,
                                                   const float* __restrict__ ed,
                                                   const int* __restrict__ indptr,
                                                   const int* __restrict__ srcs,
                                                   const float* __restrict__ bias,
                                                   unsigned short* __restrict__ Phi,
                                                   unsigned short* __restrict__ Plo) {
    int node = (blockIdx.x * blockDim.x + threadIdx.x) >> 6;
    if (node >= NN) return;
    int lane = threadIdx.x & 63;
    int head = lane >> 3;
    int b0 = indptr[node], e0 = indptr[node + 1];
    float edv = ed[node * NH + head];
    float4 a[4];
    float s[4];
    #pragma unroll
    for (int u = 0; u < 4; ++u) { a[u] = (float4){0.f, 0.f, 0.f, 0.f}; s[u] = 0.f; }
    int j = b0;
    for (; j + 3 < e0; j += 4) {
        #pragma unroll
        for (int u = 0; u < 4; ++u) {
            int x = srcs[j + u];
            float e = es[x * NH + head] + edv;
            e = (e > 0.f) ? e : 0.2f * e;
            float4 hv = *(const float4*)(H + (size_t)x * HID + lane * 4);
            float w = expf(e);
            s[u] += w;
            a[u].x = fmaf(w, hv.x, a[u].x); a[u].y = fmaf(w, hv.y, a[u].y);
            a[u].z = fmaf(w, hv.z, a[u].z); a[u].w = fmaf(w, hv.w, a[u].w);
        }
    }
    for (; j < e0; ++j) {
        int x = srcs[j];
        float e = es[x * NH + head] + edv;
        e = (e > 0.f) ? e : 0.2f * e;
        float4 hv = *(const float4*)(H + (size_t)x * HID + lane * 4);
        float w = expf(e);
        s[0] += w;
        a[0].x = fmaf(w, hv.x, a[0].x); a[0].y = fmaf(w, hv.y, a[0].y);
        a[0].z = fmaf(w, hv.z, a[0].z); a[0].w = fmaf(w, hv.w, a[0].w);
    }
    float sum = (s[0] + s[1]) + (s[2] + s[3]);
    float ax = (a[0].x + a[1].x) + (a[2].x + a[3].x);
    float ay = (a[0].y + a[1].y) + (a[2].y + a[3].y);
    float az = (a[0].z + a[1].z) + (a[2].z + a[3].z);
    float aw = (a[0].w + a[1].w) + (a[2].w + a[3].w);
    float inv = 1.f / (sum + 1e-16f);
    float4 bv = *(const float4*)(bias + lane * 4);
    float o[4];
    o[0] = fmaxf(fmaf(ax, inv, bv.x), 0.f);
    o[1] = fmaxf(fmaf(ay, inv, bv.y), 0.f);
    o[2] = fmaxf(fmaf(az, inv, bv.z), 0.f);
    o[3] = fmaxf(fmaf(aw, inv, bv.w), 0.f);
    ushort4 hv, lv;
    f2hilo(o[0], hv.x, lv.x); f2hilo(o[1], hv.y, lv.y);
    f2hilo(o[2], hv.z, lv.z); f2hilo(o[3], hv.w, lv.w);
    *(ushort4*)(Phi + (size_t)node * HID + lane * 4) = hv;
    *(ushort4*)(Plo + (size_t)node * HID + lane * 4) = lv;
}

// ---------------- per-graph max pool + linear head ----------------
__global__ void k_pool(const unsigned short* __restrict__ Phi,
                       const unsigned short* __restrict__ Plo,
                       const int* __restrict__ starts,
                       const float* __restrict__ fw, const float* __restrict__ fb,
                       float* __restrict__ out) {
    int g = (blockIdx.x * blockDim.x + threadIdx.x) >> 6;
    if (g >= GG) return;
    int lane = threadIdx.x & 63;
    int s = starts[g], e = starts[g + 1];
    float mx0 = -FLT_MAX, mx1 = -FLT_MAX, mx2 = -FLT_MAX, mx3 = -FLT_MAX;
    for (int n = s; n < e; ++n) {
        ushort4 hv = *(const ushort4*)(Phi + (size_t)n * HID + lane * 4);
        ushort4 lv = *(const ushort4*)(Plo + (size_t)n * HID + lane * 4);
        mx0 = fmaxf(mx0, bf2f(hv.x) + bf2f(lv.x));
        mx1 = fmaxf(mx1, bf2f(hv.y) + bf2f(lv.y));
        mx2 = fmaxf(mx2, bf2f(hv.z) + bf2f(lv.z));
        mx3 = fmaxf(mx3, bf2f(hv.w) + bf2f(lv.w));
    }
    float4 w = *(const float4*)(fw + lane * 4);
    float t = mx0 * w.x + mx1 * w.y + mx2 * w.z + mx3 * w.w;
    #pragma unroll
    for (int off = 32; off >= 1; off >>= 1) t += __shfl_xor(t, off, 64);
    if (lane == 0) out[g] = t + fb[0];
}

// ---------------- launcher ----------------
extern "C" void kernel_launch(void* const* d_in, const int* in_sizes, int n_in,
                              void* d_out, int out_size, void* d_ws, size_t ws_size,
                              hipStream_t stream) {
    const int* x_ids = (const int*)d_in[0];
    const int* eidx  = (const int*)d_in[1];
    const int* batch = (const int*)d_in[2];
    const float* emb = (const float*)d_in[3];
    const float* fw  = (const float*)d_in[4];
    const float* fb  = (const float*)d_in[5];
    const float* Wl[5], *asl[5], *adl[5], *bl[5];
    for (int l = 0; l < 5; ++l) {
        Wl[l]  = (const float*)d_in[6 + 4 * l];
        asl[l] = (const float*)d_in[7 + 4 * l];
        adl[l] = (const float*)d_in[8 + 4 * l];
        bl[l]  = (const float*)d_in[9 + 4 * l];
    }

    char* ws = (char*)d_ws;
    size_t off = 0;
    auto alloc = [&](size_t bytes) {
        void* p = ws + off;
        off = (off + bytes + 255) & ~(size_t)255;
        return p;
    };
    unsigned short* Phi  = (unsigned short*)alloc((size_t)NP * HID * 2);
    unsigned short* Plo  = (unsigned short*)alloc((size_t)NP * HID * 2);
    float* Q     = (float*)alloc((size_t)NN * HID * 4);
    unsigned short* Whi  = (unsigned short*)alloc((size_t)5 * HID * HID * 2);
    unsigned short* Wlo  = (unsigned short*)alloc((size_t)5 * HID * HID * 2);
    unsigned short* Wthi = (unsigned short*)alloc((size_t)5 * 16 * HID * 2);
    unsigned short* Wtlo = (unsigned short*)alloc((size_t)5 * 16 * HID * 2);
    float* es    = (float*)alloc((size_t)NN * NH * 4);
    float* ed    = (float*)alloc((size_t)NN * NH * 4);
    int* cnt     = (int*)alloc((size_t)NN * 4);
    int* cursor  = (int*)alloc((size_t)NN * 4);
    int* indptr  = (int*)alloc((size_t)(NN + 1) * 4);
    int* srcs    = (int*)alloc((size_t)EP * 4);
    int* starts  = (int*)alloc((size_t)(GG + 1) * 4);
    (void)ws_size; (void)in_sizes; (void)n_in; (void)out_size;

    hipMemsetAsync(cnt, 0, (size_t)NN * 4, stream);
    hipMemsetAsync(cursor, 0, (size_t)NN * 4, stream);

    k_hist<<<(EP + 255) / 256, 256, 0, stream>>>(eidx + EE, cnt);
    k_scan<<<1, 1024, 0, stream>>>(cnt, indptr);
    k_fill<<<(EP + 255) / 256, 256, 0, stream>>>(eidx, eidx + EE, indptr, cursor, srcs);
    k_sortseg<<<(NN + 255) / 256, 256, 0, stream>>>(srcs, indptr);
    k_starts<<<(NN + 255) / 256, 256, 0, stream>>>(batch, starts);
    k_wconv<<<dim3(HID * HID / 256, 5), 256, 0, stream>>>(Wl[0], Wl[1], Wl[2], Wl[3], Wl[4], Whi, Wlo);
    for (int l = 0; l < 5; ++l)
        k_wtilde<<<16, 256, 0, stream>>>(Wl[l], asl[l], adl[l],
                                         Wthi + (size_t)l * 16 * HID,
                                         Wtlo + (size_t)l * 16 * HID);
    k_embed<<<NN / 4, 256, 0, stream>>>(x_ids, emb, Phi, Plo);

    for (int l = 0; l < 5; ++l) {
        dim3 gg(NP / 128, HID / 128);
        k_gemm<<<gg, 256, 0, stream>>>(Phi, Plo,
                                       Whi + (size_t)l * HID * HID,
                                       Wlo + (size_t)l * HID * HID,
                                       Wthi + (size_t)l * 16 * HID,
                                       Wtlo + (size_t)l * 16 * HID,
                                       Q, es, ed, NN);
        k_aggregate<<<NN / 4, 256, 0, stream>>>(Q, es, ed, indptr, srcs, bl[l], Phi, Plo);
    }
    k_pool<<<GG / 4, 256, 0, stream>>>(Phi, Plo, starts, fw, fb, (float*)d_out);
}